// Round 12
// baseline (287.598 us; speedup 1.0000x reference)
//
#include <hip/hip_runtime.h>
#include <hip/hip_bf16.h>

// Problem constants (B=8, L=4096, D=1024, S=256)
#define BB 8
#define LL 4096
#define DD 1024
#define SS 256
#define NTOK (BB * LL)  // 32768 tokens
#define CCH 64          // chunks per sequence (parallel scan)
#define TCH (LL / CCH)  // 64 timesteps per chunk

typedef short bf16x8 __attribute__((ext_vector_type(8)));
typedef float f32x4 __attribute__((ext_vector_type(4)));

__device__ __forceinline__ float bfu(unsigned short v) {
  union { unsigned int i; float f; } x;
  x.i = ((unsigned int)v) << 16;
  return x.f;
}

// Async global->LDS, 16B per lane. LDS dest is wave-uniform base + lane*16.
__device__ __forceinline__ void gl_lds16(const __hip_bfloat16* g, void* l) {
  __builtin_amdgcn_global_load_lds(
      (const __attribute__((address_space(1))) unsigned int*)g,
      (__attribute__((address_space(3))) unsigned int*)l, 16, 0, 0);
}

// ---------------------------------------------------------------------------
// Kernel 1: RMSNorm + bf16 cast.  One block per token row (D=1024).
// ---------------------------------------------------------------------------
__global__ __launch_bounds__(256) void prep_rms(const float* __restrict__ x,
                                                const float* __restrict__ wn,
                                                __hip_bfloat16* __restrict__ xn) {
  const size_t row = blockIdx.x;
  const int t = threadIdx.x;
  const float4 xv = reinterpret_cast<const float4*>(x + row * DD)[t];
  const float4 wv = reinterpret_cast<const float4*>(wn)[t];
  float ss = xv.x * xv.x + xv.y * xv.y + xv.z * xv.z + xv.w * xv.w;
#pragma unroll
  for (int m = 32; m >= 1; m >>= 1) ss += __shfl_xor(ss, m);
  __shared__ float red[4];
  if ((t & 63) == 0) red[t >> 6] = ss;
  __syncthreads();
  const float tot = red[0] + red[1] + red[2] + red[3];
  const float r = rsqrtf(tot * (1.0f / DD) + 1e-8f);
  union { ushort4 u; __hip_bfloat16 h[4]; } o;
  o.h[0] = __float2bfloat16(xv.x * wv.x * r);
  o.h[1] = __float2bfloat16(xv.y * wv.y * r);
  o.h[2] = __float2bfloat16(xv.z * wv.z * r);
  o.h[3] = __float2bfloat16(xv.w * wv.w * r);
  reinterpret_cast<ushort4*>(xn + row * DD)[t] = o.u;
}

// ---------------------------------------------------------------------------
// Kernel 2: all four weight transposes+casts in one launch (blockIdx.y = seg).
// WT[n*K+k] = bf16(W[k*Nw+n])
// ---------------------------------------------------------------------------
__global__ __launch_bounds__(256) void convT4(
    const float* __restrict__ W0, const float* __restrict__ W1,
    const float* __restrict__ W2, const float* __restrict__ W3,
    __hip_bfloat16* __restrict__ T0, __hip_bfloat16* __restrict__ T1,
    __hip_bfloat16* __restrict__ T2, __hip_bfloat16* __restrict__ T3) {
  const int seg = blockIdx.y;
  const int K = (seg == 0) ? DD : SS;
  const int Nw = (seg == 0) ? 768 : (seg == 3) ? DD : SS;
  const float* W = (seg == 0) ? W0 : (seg == 1) ? W1 : (seg == 2) ? W2 : W3;
  __hip_bfloat16* T = (seg == 0) ? T0 : (seg == 1) ? T1 : (seg == 2) ? T2 : T3;
  const int idx = blockIdx.x * 256 + threadIdx.x;
  if (idx >= K * Nw) return;
  const int k = idx / Nw, n = idx % Nw;
  T[(size_t)n * K + k] = __float2bfloat16(W[idx]);
}

// ---------------------------------------------------------------------------
// Kernel 3: bf16 MFMA GEMM.  C[M,Nt] = epi(A[M,K] @ BT[Nt,K]^T + bias)
// 128x128 tile, 4 waves, BK=32, 4-BUFFER LDS RING with DEPTH-3 prefetch:
//   at iter t issue tile t+3's loads (buffer freed at t-1's trailing barrier),
//   counted vmcnt(12) keeps 3 tiles in flight -> ~900+ cyc latency cover
//   (HBM miss ~900 cyc; depth-1 at BK=64 only covered ~300).  [T4 deepened]
// Both-sides XOR swizzle for 64B rows: key=(row>>1)&3 -> 2-way (free) banks.
// Swapped MFMA operands: D rows = tokens, 4 consecutive C-cols per acc reg.
// EPI 3: NT resid loads + bias pinned by sched_barrier(0); plain f32x4 stores.
// EPI 4: fused g1+g2 (blockIdx.y>>1 selects {WxT,b_x,tanh->ut} vs
// {WdtT,b_dt,sigmoid->dtb}), K=256.
// EPI: 0 = bf16, 1 = tanh, 2 = sigmoid, 3 = +resid->f32, 4 = fused g1/g2
// ---------------------------------------------------------------------------
template <int EPI>
__global__ __launch_bounds__(256, 2) void gemm_bf16(
    const __hip_bfloat16* __restrict__ A, int lda,
    const __hip_bfloat16* __restrict__ BT,  // [Nt][K] (pre-transposed)
    const float* __restrict__ bias,
    void* __restrict__ Cptr, int ldc,
    const float* __restrict__ resid,
    int K,
    const __hip_bfloat16* __restrict__ BT2,
    const float* __restrict__ bias2,
    void* __restrict__ Cptr2) {
  // 4-buffer ring: per buffer 128 rows x 64 B (BK=32 bf16) per operand.
  __shared__ __align__(16) char ldsA[4 * 8192];
  __shared__ __align__(16) char ldsB[4 * 8192];

  const int t = threadIdx.x;
  const int bm = blockIdx.x;
  const int bn = blockIdx.y;
  const int wave = t >> 6, lane = t & 63;
  const int wr = (wave >> 1) * 64;
  const int wc = (wave & 1) * 64;
  const int lr = lane & 15;
  const int kg = lane >> 4;
  const int rkey = (lr >> 1) & 3;   // read-side swizzle key

  // EPI 4: which GEMM (0 = u/tanh, 1 = z/sigmoid); bneff = column tile.
  const int which = (EPI == 4) ? (bn >> 1) : 0;
  const int bneff = (EPI == 4) ? (bn & 1) : bn;
  const __hip_bfloat16* Aeff = (EPI == 4 && which) ? A + SS : A;
  const __hip_bfloat16* BTeff = (EPI == 4 && which) ? BT2 : BT;
  const float* biaseff = (EPI == 4 && which) ? bias2 : bias;
  void* Ceff = (EPI == 4 && which) ? Cptr2 : Cptr;

  // Staging: per gl_lds16 a wave writes 16 rows x 64 B.  Lane l -> row
  // (l>>2), LDS slot (l&3).  Global source slot pre-swizzled so that
  // LDS[r][s] holds global chunk s ^ ((r>>1)&3); key reduces to (l>>3)&3.
  const int sg = (lane & 3) ^ ((lane >> 3) & 3);
  const int s_row = wave * 32 + (lane >> 2);
  const __hip_bfloat16* Ab = Aeff + (size_t)(bm * 128 + s_row) * lda + sg * 8;
  const __hip_bfloat16* Bb = BTeff + (size_t)(bneff * 128 + s_row) * K + sg * 8;

  f32x4 acc[4][4] = {};

  // One STAGE = one BK=32 tile = 4 gl_lds16 per thread (2 x A + 2 x B).
#define STAGE(d, koff)                                                        \
  {                                                                           \
    _Pragma("unroll") for (int p = 0; p < 2; ++p) {                           \
      gl_lds16(Ab + (size_t)(p * 16) * lda + (koff),                          \
               ldsA + (d) * 8192 + (wave * 32 + p * 16) * 64);                \
      gl_lds16(Bb + (size_t)(p * 16) * K + (koff),                            \
               ldsB + (d) * 8192 + (wave * 32 + p * 16) * 64);                \
    }                                                                         \
  }

  const int NT = K >> 5;  // BK=32 tiles
  STAGE(0, 0);
  STAGE(1, 32);
  STAGE(2, 64);

  for (int ti = 0; ti < NT; ++ti) {
    // Issue tile ti+3 into the ring slot freed at iteration ti-1.
    if (ti + 3 < NT) {
      STAGE((ti + 3) & 3, (ti + 3) * 32);
      asm volatile("s_waitcnt vmcnt(12)" ::: "memory");  // tile ti landed
    } else if (ti + 2 < NT) {
      asm volatile("s_waitcnt vmcnt(8)" ::: "memory");
    } else if (ti + 1 < NT) {
      asm volatile("s_waitcnt vmcnt(4)" ::: "memory");
    } else {
      asm volatile("s_waitcnt vmcnt(0)" ::: "memory");
    }
    __builtin_amdgcn_sched_barrier(0);
    __builtin_amdgcn_s_barrier();   // all waves' tile-ti loads visible

    const char* bufA = ldsA + (ti & 3) * 8192;
    const char* bufB = ldsB + (ti & 3) * 8192;
    bf16x8 af[4], bfr[4];
#pragma unroll
    for (int m = 0; m < 4; ++m) {
      const int row = wr + m * 16 + lr;
      const int slot = kg ^ rkey;
      af[m] = *reinterpret_cast<const bf16x8*>(bufA + row * 64 + slot * 16);
    }
#pragma unroll
    for (int n = 0; n < 4; ++n) {
      const int row = wc + n * 16 + lr;
      const int slot = kg ^ rkey;
      bfr[n] = *reinterpret_cast<const bf16x8*>(bufB + row * 64 + slot * 16);
    }
#pragma unroll
    for (int m = 0; m < 4; ++m)
#pragma unroll
      for (int n = 0; n < 4; ++n)
        acc[m][n] = __builtin_amdgcn_mfma_f32_16x16x32_bf16(bfr[n], af[m],
                                                            acc[m][n], 0, 0, 0);
    __builtin_amdgcn_sched_barrier(0);
    __builtin_amdgcn_s_barrier();   // reads done before ring slot reuse
  }
#undef STAGE

  // Swapped-operand epilogue:
  // token row = bm*128 + wr + m*16 + (lane&15)
  // C col     = bneff*128 + wc + n*16 + kg*4 + j   (j = 0..3 consecutive)
  const int row0 = bm * 128 + wr + lr;
  const int col0 = bneff * 128 + wc + kg * 4;

  if (EPI == 3) {
    // Issue ALL 16 resid loads (NT) + 4 bias loads, then PIN with
    // sched_barrier(0) so the compiler cannot sink them to their uses.
    f32x4 rv[4][4];
    f32x4 bv[4];
#pragma unroll
    for (int n = 0; n < 4; ++n)
      bv[n] = *reinterpret_cast<const f32x4*>(&bias[col0 + n * 16]);
#pragma unroll
    for (int m = 0; m < 4; ++m) {
      const size_t rowoff = (size_t)(row0 + m * 16) * ldc;
#pragma unroll
      for (int n = 0; n < 4; ++n) {
        rv[m][n] = __builtin_nontemporal_load(
            reinterpret_cast<const f32x4*>(&resid[rowoff + col0 + n * 16]));
      }
    }
    __builtin_amdgcn_sched_barrier(0);  // all 16 loads stay issued up-front
#pragma unroll
    for (int m = 0; m < 4; ++m) {
      const size_t rowoff = (size_t)(row0 + m * 16) * ldc;
#pragma unroll
      for (int n = 0; n < 4; ++n) {
        f32x4 ov = acc[m][n] + bv[n] + rv[m][n];
        *reinterpret_cast<f32x4*>(&((float*)Cptr)[rowoff + col0 + n * 16]) = ov;
      }
    }
  } else {
#pragma unroll
    for (int m = 0; m < 4; ++m) {
      const int row = row0 + m * 16;
#pragma unroll
      for (int n = 0; n < 4; ++n) {
        const int colb = col0 + n * 16;
        const float4 bvv = *reinterpret_cast<const float4*>(&biaseff[colb]);
        float v0 = acc[m][n][0] + bvv.x;
        float v1 = acc[m][n][1] + bvv.y;
        float v2 = acc[m][n][2] + bvv.z;
        float v3 = acc[m][n][3] + bvv.w;
        if (EPI == 1 || (EPI == 4 && which == 0)) {
          v0 = tanhf(v0); v1 = tanhf(v1); v2 = tanhf(v2); v3 = tanhf(v3);
        } else if (EPI == 2 || (EPI == 4 && which == 1)) {
          v0 = 1.f / (1.f + expf(-v0)); v1 = 1.f / (1.f + expf(-v1));
          v2 = 1.f / (1.f + expf(-v2)); v3 = 1.f / (1.f + expf(-v3));
        }
        union { ushort4 u; __hip_bfloat16 h[4]; } o;
        o.h[0] = __float2bfloat16(v0); o.h[1] = __float2bfloat16(v1);
        o.h[2] = __float2bfloat16(v2); o.h[3] = __float2bfloat16(v3);
        *reinterpret_cast<ushort4*>(
            &((__hip_bfloat16*)Ceff)[(size_t)row * ldc + colb]) = o.u;
      }
    }
  }
}

// ---------------------------------------------------------------------------
// Kernel 4a: chunked scan phase A.  Per (b, chunk, s): local scan from h=0
// giving h0, and decay product A = prod(1-d).  2 channels per lane (ushort2).
// ---------------------------------------------------------------------------
__global__ __launch_bounds__(128) void scan_phase_a(
    const __hip_bfloat16* __restrict__ ut,
    const __hip_bfloat16* __restrict__ dtb,
    float* __restrict__ h0s, float* __restrict__ As) {
  const int bc = blockIdx.x;             // b*CCH + c
  const int b = bc / CCH, c = bc % CCH;
  const int ch = threadIdx.x * 2;        // channel pair base
  const size_t base = ((size_t)b * LL + (size_t)c * TCH) * SS + ch;
  float h0 = 0.f, h1 = 0.f, A0 = 1.f, A1 = 1.f;
#pragma unroll 8
  for (int t = 0; t < TCH; ++t) {
    const ushort2 uu = *reinterpret_cast<const ushort2*>(ut + base + (size_t)t * SS);
    const ushort2 dd = *reinterpret_cast<const ushort2*>(dtb + base + (size_t)t * SS);
    const float d0 = bfu(dd.x), d1 = bfu(dd.y);
    h0 = fmaf(d0, bfu(uu.x) - h0, h0);
    h1 = fmaf(d1, bfu(uu.y) - h1, h1);
    A0 *= (1.f - d0);
    A1 *= (1.f - d1);
  }
  const size_t o = (size_t)bc * SS + ch;
  *reinterpret_cast<float2*>(h0s + o) = make_float2(h0, h1);
  *reinterpret_cast<float2*>(As + o) = make_float2(A0, A1);
}

// ---------------------------------------------------------------------------
// Kernel 4b: carry scan over chunk summaries.  Per (b, s): hin_0 = 0,
// hin_{c+1} = h0_c + A_c * hin_c.  Stores hin per (b, c, s).
// ---------------------------------------------------------------------------
__global__ __launch_bounds__(256) void scan_phase_b(
    const float* __restrict__ h0s, const float* __restrict__ As,
    float* __restrict__ hins) {
  const int b = blockIdx.x;
  const int s = threadIdx.x;
  float hin = 0.f;
#pragma unroll 8
  for (int c = 0; c < CCH; ++c) {
    const size_t idx = ((size_t)b * CCH + c) * SS + s;
    hins[idx] = hin;
    hin = fmaf(As[idx], hin, h0s[idx]);
  }
}

// ---------------------------------------------------------------------------
// Kernel 4c: chunked scan phase C.  Re-run each chunk with correct carry-in,
// gate by sigmoid(g), write hsg (in-place over ut: same-thread read-first).
// ---------------------------------------------------------------------------
__global__ __launch_bounds__(128) void scan_phase_c(
    const __hip_bfloat16* __restrict__ ut,
    const __hip_bfloat16* __restrict__ dtb,
    const __hip_bfloat16* __restrict__ gz,   // uzg + 512, row stride 768
    const float* __restrict__ hins,
    __hip_bfloat16* __restrict__ hsg) {
  const int bc = blockIdx.x;
  const int b = bc / CCH, c = bc % CCH;
  const int ch = threadIdx.x * 2;
  const size_t rowbase = (size_t)b * LL + (size_t)c * TCH;
  const float2 hv = *reinterpret_cast<const float2*>(hins + (size_t)bc * SS + ch);
  float h0 = hv.x, h1 = hv.y;
#pragma unroll 8
  for (int t = 0; t < TCH; ++t) {
    const size_t row = rowbase + t;
    const ushort2 uu = *reinterpret_cast<const ushort2*>(ut + row * SS + ch);
    const ushort2 dd = *reinterpret_cast<const ushort2*>(dtb + row * SS + ch);
    const ushort2 gg = *reinterpret_cast<const ushort2*>(gz + row * 768 + ch);
    h0 = fmaf(bfu(dd.x), bfu(uu.x) - h0, h0);
    h1 = fmaf(bfu(dd.y), bfu(uu.y) - h1, h1);
    union { ushort2 u; __hip_bfloat16 h[2]; } o;
    o.h[0] = __float2bfloat16(h0 / (1.f + expf(-bfu(gg.x))));
    o.h[1] = __float2bfloat16(h1 / (1.f + expf(-bfu(gg.y))));
    *reinterpret_cast<ushort2*>(hsg + row * SS + ch) = o.u;
  }
}

// ---------------------------------------------------------------------------
extern "C" void kernel_launch(void* const* d_in, const int* in_sizes, int n_in,
                              void* d_out, int out_size, void* d_ws, size_t ws_size,
                              hipStream_t stream) {
  const float* x      = (const float*)d_in[0];
  const float* w_norm = (const float*)d_in[1];
  const float* W_in   = (const float*)d_in[2];
  const float* b_in   = (const float*)d_in[3];
  const float* W_x    = (const float*)d_in[4];
  const float* b_x    = (const float*)d_in[5];
  const float* W_dt   = (const float*)d_in[6];
  const float* b_dt   = (const float*)d_in[7];
  const float* W_out  = (const float*)d_in[8];
  const float* b_out  = (const float*)d_in[9];
  float* out = (float*)d_out;

  // Workspace layout (bf16 buffers). ut/dt alias the dead xn region.
  char* w = (char*)d_ws;
  __hip_bfloat16* xn  = (__hip_bfloat16*)w;                 // NTOK*1024
  __hip_bfloat16* ut  = (__hip_bfloat16*)w;                 // NTOK*256 (after GEMM1)
  __hip_bfloat16* dtb = (__hip_bfloat16*)(w + (size_t)NTOK * SS * 2);
  w += (size_t)NTOK * DD * 2;                               // 64 MiB
  __hip_bfloat16* uzg = (__hip_bfloat16*)w;  w += (size_t)NTOK * 768 * 2;  // 48 MiB
  __hip_bfloat16* WinT  = (__hip_bfloat16*)w;  w += (size_t)768 * DD * 2;
  __hip_bfloat16* WxT   = (__hip_bfloat16*)w;  w += (size_t)SS * SS * 2;
  __hip_bfloat16* WdtT  = (__hip_bfloat16*)w;  w += (size_t)SS * SS * 2;
  __hip_bfloat16* WoutT = (__hip_bfloat16*)w;  w += (size_t)DD * SS * 2;
  float* h0s  = (float*)w;  w += (size_t)BB * CCH * SS * 4;   // 512 KiB
  float* As   = (float*)w;  w += (size_t)BB * CCH * SS * 4;
  float* hins = (float*)w;  w += (size_t)BB * CCH * SS * 4;
  (void)ws_size; (void)n_in; (void)in_sizes; (void)out_size;

  // Stage 0: all weight conversions in one launch
  convT4<<<dim3((DD * 768 + 255) / 256, 4), 256, 0, stream>>>(
      W_in, W_x, W_dt, W_out, WinT, WxT, WdtT, WoutT);

  // Stage 1: RMSNorm -> xn (bf16)
  prep_rms<<<NTOK, 256, 0, stream>>>(x, w_norm, xn);

  // Stage 2: uzg = xn @ W_in + b_in   (M=32768, N=768, K=1024)
  gemm_bf16<0><<<dim3(NTOK / 128, 768 / 128), 256, 0, stream>>>(
      xn, DD, WinT, b_in, uzg, 768, nullptr, DD, nullptr, nullptr, nullptr);

  // Stage 3 (fused): ut = tanh(u @ W_x + b_x); dt = sigmoid(z @ W_dt + b_dt)
  gemm_bf16<4><<<dim3(NTOK / 128, 4), 256, 0, stream>>>(
      uzg, 768, WxT, b_x, ut, SS, nullptr, SS, WdtT, b_dt, dtb);

  // Stage 4: chunked parallel scan + gate (in-place hsg over ut buffer)
  scan_phase_a<<<BB * CCH, 128, 0, stream>>>(ut, dtb, h0s, As);
  scan_phase_b<<<BB, 256, 0, stream>>>(h0s, As, hins);
  scan_phase_c<<<BB * CCH, 128, 0, stream>>>(ut, dtb, uzg + 2 * SS, hins, ut);

  // Stage 5: out = x + hsg @ W_out + b_out  (M=32768, N=1024, K=256)
  gemm_bf16<3><<<dim3(NTOK / 128, DD / 128), 256, 0, stream>>>(
      ut, SS, WoutT, b_out, out, DD, x, SS, nullptr, nullptr, nullptr);
}

// Round 13
// 285.844 us; speedup vs baseline: 1.0061x; 1.0061x over previous
//
#include <hip/hip_runtime.h>
#include <hip/hip_bf16.h>

// Problem constants (B=8, L=4096, D=1024, S=256)
#define BB 8
#define LL 4096
#define DD 1024
#define SS 256
#define NTOK (BB * LL)  // 32768 tokens
#define CCH 64          // chunks per sequence (parallel scan)
#define TCH (LL / CCH)  // 64 timesteps per chunk

typedef short bf16x8 __attribute__((ext_vector_type(8)));
typedef float f32x4 __attribute__((ext_vector_type(4)));

__device__ __forceinline__ float bfu(unsigned short v) {
  union { unsigned int i; float f; } x;
  x.i = ((unsigned int)v) << 16;
  return x.f;
}

// Async global->LDS, 16B per lane. LDS dest is wave-uniform base + lane*16.
__device__ __forceinline__ void gl_lds16(const __hip_bfloat16* g, void* l) {
  __builtin_amdgcn_global_load_lds(
      (const __attribute__((address_space(1))) unsigned int*)g,
      (__attribute__((address_space(3))) unsigned int*)l, 16, 0, 0);
}

// ---------------------------------------------------------------------------
// Kernel 1: RMSNorm + bf16 cast.  One block per token row (D=1024).
// ---------------------------------------------------------------------------
__global__ __launch_bounds__(256) void prep_rms(const float* __restrict__ x,
                                                const float* __restrict__ wn,
                                                __hip_bfloat16* __restrict__ xn) {
  const size_t row = blockIdx.x;
  const int t = threadIdx.x;
  const float4 xv = reinterpret_cast<const float4*>(x + row * DD)[t];
  const float4 wv = reinterpret_cast<const float4*>(wn)[t];
  float ss = xv.x * xv.x + xv.y * xv.y + xv.z * xv.z + xv.w * xv.w;
#pragma unroll
  for (int m = 32; m >= 1; m >>= 1) ss += __shfl_xor(ss, m);
  __shared__ float red[4];
  if ((t & 63) == 0) red[t >> 6] = ss;
  __syncthreads();
  const float tot = red[0] + red[1] + red[2] + red[3];
  const float r = rsqrtf(tot * (1.0f / DD) + 1e-8f);
  union { ushort4 u; __hip_bfloat16 h[4]; } o;
  o.h[0] = __float2bfloat16(xv.x * wv.x * r);
  o.h[1] = __float2bfloat16(xv.y * wv.y * r);
  o.h[2] = __float2bfloat16(xv.z * wv.z * r);
  o.h[3] = __float2bfloat16(xv.w * wv.w * r);
  reinterpret_cast<ushort4*>(xn + row * DD)[t] = o.u;
}

// ---------------------------------------------------------------------------
// Kernel 2: all four weight transposes+casts in one launch (blockIdx.y = seg).
// WT[n*K+k] = bf16(W[k*Nw+n])
// ---------------------------------------------------------------------------
__global__ __launch_bounds__(256) void convT4(
    const float* __restrict__ W0, const float* __restrict__ W1,
    const float* __restrict__ W2, const float* __restrict__ W3,
    __hip_bfloat16* __restrict__ T0, __hip_bfloat16* __restrict__ T1,
    __hip_bfloat16* __restrict__ T2, __hip_bfloat16* __restrict__ T3) {
  const int seg = blockIdx.y;
  const int K = (seg == 0) ? DD : SS;
  const int Nw = (seg == 0) ? 768 : (seg == 3) ? DD : SS;
  const float* W = (seg == 0) ? W0 : (seg == 1) ? W1 : (seg == 2) ? W2 : W3;
  __hip_bfloat16* T = (seg == 0) ? T0 : (seg == 1) ? T1 : (seg == 2) ? T2 : T3;
  const int idx = blockIdx.x * 256 + threadIdx.x;
  if (idx >= K * Nw) return;
  const int k = idx / Nw, n = idx % Nw;
  T[(size_t)n * K + k] = __float2bfloat16(W[idx]);
}

// ---------------------------------------------------------------------------
// Kernel 3a: 8-phase-style GEMM for g0 (M=32768, N=768, K=1024).
// BM=256 x BN=128, BK=64, 8 waves (4M x 2N, wave-tile 64x64), TRI-buffered
// LDS (144 KB), depth-2 prefetch with counted vmcnt(6) (never 0 mid-loop).
// Per K-tile: 4 fine phases, each {ds_read frag subset; 2 gl_lds stage;
// lgkmcnt(0)+sched_barrier; setprio(1); 8 MFMA; setprio(0); s_barrier}.
// Both-sides XOR swizzle; swapped MFMA operands (D rows = tokens).
// ---------------------------------------------------------------------------
__global__ __launch_bounds__(512, 2) void gemm0_8p(
    const __hip_bfloat16* __restrict__ A,   // xn [32768][1024]
    const __hip_bfloat16* __restrict__ BT,  // WinT [768][1024]
    const float* __restrict__ bias,
    __hip_bfloat16* __restrict__ C) {       // uzg [32768][768]
  __shared__ __align__(16) char ldsA[3 * 32768];  // 3 x 256 rows x 128 B
  __shared__ __align__(16) char ldsB[3 * 16384];  // 3 x 128 rows x 128 B

  const int t = threadIdx.x;
  const int bm = blockIdx.x, bn = blockIdx.y;
  const int wave = t >> 6, lane = t & 63;
  const int wm = wave >> 1, wn = wave & 1;
  const int wr = wm * 64, wc = wn * 64;
  const int lr = lane & 15;
  const int kg = lane >> 4;
  const int rsw = lr & 7;

  // Staging: per gl_lds a wave covers 8 rows x 128 B.  Lane l -> row l>>3,
  // slot l&7; global slot pre-swizzled: LDS[r][s] = global chunk s ^ (r&7).
  const int srow = lane >> 3;
  const int sg = (lane & 7) ^ srow;
  const __hip_bfloat16* Abase = A + (size_t)(bm * 256) * DD + sg * 8;
  const __hip_bfloat16* Bbase = BT + (size_t)(bn * 128) * DD + sg * 8;

  f32x4 acc[4][4] = {};

  // Stage one 8-row group (A half h, group p) / (B group p) of tile at koff.
#define STA(buf, h, p, koff)                                                  \
  gl_lds16(Abase + (size_t)((h)*128 + wave * 16 + (p)*8 + srow) * DD + (koff),\
           ldsA + (buf)*32768 + ((h)*128 + wave * 16 + (p)*8) * 128)
#define STB(buf, p, koff)                                                     \
  gl_lds16(Bbase + (size_t)(wave * 16 + (p)*8 + srow) * DD + (koff),          \
           ldsB + (buf)*16384 + (wave * 16 + (p)*8) * 128)
#define LDA_(row, slot) \
  (*reinterpret_cast<const bf16x8*>(bufA + (row)*128 + (slot)*16))
#define LDB_(row, slot) \
  (*reinterpret_cast<const bf16x8*>(bufB + (row)*128 + (slot)*16))

  const int NT = DD / 64;  // 16 K-tiles
  // Prologue: stage tiles 0 (buf0) and 1 (buf1): 6 loads each per wave.
#pragma unroll
  for (int p = 0; p < 2; ++p) {
    STA(0, 0, p, 0); STA(0, 1, p, 0); STB(0, p, 0);
  }
#pragma unroll
  for (int p = 0; p < 2; ++p) {
    STA(1, 0, p, 64); STA(1, 1, p, 64); STB(1, p, 64);
  }

  for (int ti = 0; ti < NT; ++ti) {
    if (ti < NT - 1) {
      asm volatile("s_waitcnt vmcnt(6)" ::: "memory");  // tile ti landed
    } else {
      asm volatile("s_waitcnt vmcnt(0)" ::: "memory");
    }
    __builtin_amdgcn_sched_barrier(0);
    __builtin_amdgcn_s_barrier();  // all waves' tile-ti loads visible

    const int cb = ti % 3;
    const int sb = (ti + 2) % 3;
    const bool st = (ti + 2) < NT;
    const int koff = (ti + 2) * 64;
    const char* bufA = ldsA + cb * 32768;
    const char* bufB = ldsB + cb * 16384;

    bf16x8 a0, a1, a2, a3, b0, b1, b2, b3;
    // ---- phase 0: kh=0 reads (a0,a1 + b0..b3); stage A-half0; mfma m0,m1
    {
      const int s0 = kg ^ rsw;
      a0 = LDA_(wr + 0 * 16 + lr, s0);
      a1 = LDA_(wr + 1 * 16 + lr, s0);
      b0 = LDB_(wc + 0 * 16 + lr, s0);
      b1 = LDB_(wc + 1 * 16 + lr, s0);
      b2 = LDB_(wc + 2 * 16 + lr, s0);
      b3 = LDB_(wc + 3 * 16 + lr, s0);
      if (st) { STA(sb, 0, 0, koff); STA(sb, 0, 1, koff); }
      asm volatile("s_waitcnt lgkmcnt(0)" ::: "memory");
      __builtin_amdgcn_sched_barrier(0);
      __builtin_amdgcn_s_setprio(1);
      acc[0][0] = __builtin_amdgcn_mfma_f32_16x16x32_bf16(b0, a0, acc[0][0], 0, 0, 0);
      acc[0][1] = __builtin_amdgcn_mfma_f32_16x16x32_bf16(b1, a0, acc[0][1], 0, 0, 0);
      acc[0][2] = __builtin_amdgcn_mfma_f32_16x16x32_bf16(b2, a0, acc[0][2], 0, 0, 0);
      acc[0][3] = __builtin_amdgcn_mfma_f32_16x16x32_bf16(b3, a0, acc[0][3], 0, 0, 0);
      acc[1][0] = __builtin_amdgcn_mfma_f32_16x16x32_bf16(b0, a1, acc[1][0], 0, 0, 0);
      acc[1][1] = __builtin_amdgcn_mfma_f32_16x16x32_bf16(b1, a1, acc[1][1], 0, 0, 0);
      acc[1][2] = __builtin_amdgcn_mfma_f32_16x16x32_bf16(b2, a1, acc[1][2], 0, 0, 0);
      acc[1][3] = __builtin_amdgcn_mfma_f32_16x16x32_bf16(b3, a1, acc[1][3], 0, 0, 0);
      __builtin_amdgcn_s_setprio(0);
      __builtin_amdgcn_s_barrier();
    }
    // ---- phase 1: kh=0 reads (a2,a3); stage A-half1; mfma m2,m3
    {
      const int s0 = kg ^ rsw;
      a2 = LDA_(wr + 2 * 16 + lr, s0);
      a3 = LDA_(wr + 3 * 16 + lr, s0);
      if (st) { STA(sb, 1, 0, koff); STA(sb, 1, 1, koff); }
      asm volatile("s_waitcnt lgkmcnt(0)" ::: "memory");
      __builtin_amdgcn_sched_barrier(0);
      __builtin_amdgcn_s_setprio(1);
      acc[2][0] = __builtin_amdgcn_mfma_f32_16x16x32_bf16(b0, a2, acc[2][0], 0, 0, 0);
      acc[2][1] = __builtin_amdgcn_mfma_f32_16x16x32_bf16(b1, a2, acc[2][1], 0, 0, 0);
      acc[2][2] = __builtin_amdgcn_mfma_f32_16x16x32_bf16(b2, a2, acc[2][2], 0, 0, 0);
      acc[2][3] = __builtin_amdgcn_mfma_f32_16x16x32_bf16(b3, a2, acc[2][3], 0, 0, 0);
      acc[3][0] = __builtin_amdgcn_mfma_f32_16x16x32_bf16(b0, a3, acc[3][0], 0, 0, 0);
      acc[3][1] = __builtin_amdgcn_mfma_f32_16x16x32_bf16(b1, a3, acc[3][1], 0, 0, 0);
      acc[3][2] = __builtin_amdgcn_mfma_f32_16x16x32_bf16(b2, a3, acc[3][2], 0, 0, 0);
      acc[3][3] = __builtin_amdgcn_mfma_f32_16x16x32_bf16(b3, a3, acc[3][3], 0, 0, 0);
      __builtin_amdgcn_s_setprio(0);
      __builtin_amdgcn_s_barrier();
    }
    // ---- phase 2: kh=1 reads (a0,a1 + b0..b3); stage B; mfma m0,m1
    {
      const int s1 = (kg + 4) ^ rsw;
      a0 = LDA_(wr + 0 * 16 + lr, s1);
      a1 = LDA_(wr + 1 * 16 + lr, s1);
      b0 = LDB_(wc + 0 * 16 + lr, s1);
      b1 = LDB_(wc + 1 * 16 + lr, s1);
      b2 = LDB_(wc + 2 * 16 + lr, s1);
      b3 = LDB_(wc + 3 * 16 + lr, s1);
      if (st) { STB(sb, 0, koff); STB(sb, 1, koff); }
      asm volatile("s_waitcnt lgkmcnt(0)" ::: "memory");
      __builtin_amdgcn_sched_barrier(0);
      __builtin_amdgcn_s_setprio(1);
      acc[0][0] = __builtin_amdgcn_mfma_f32_16x16x32_bf16(b0, a0, acc[0][0], 0, 0, 0);
      acc[0][1] = __builtin_amdgcn_mfma_f32_16x16x32_bf16(b1, a0, acc[0][1], 0, 0, 0);
      acc[0][2] = __builtin_amdgcn_mfma_f32_16x16x32_bf16(b2, a0, acc[0][2], 0, 0, 0);
      acc[0][3] = __builtin_amdgcn_mfma_f32_16x16x32_bf16(b3, a0, acc[0][3], 0, 0, 0);
      acc[1][0] = __builtin_amdgcn_mfma_f32_16x16x32_bf16(b0, a1, acc[1][0], 0, 0, 0);
      acc[1][1] = __builtin_amdgcn_mfma_f32_16x16x32_bf16(b1, a1, acc[1][1], 0, 0, 0);
      acc[1][2] = __builtin_amdgcn_mfma_f32_16x16x32_bf16(b2, a1, acc[1][2], 0, 0, 0);
      acc[1][3] = __builtin_amdgcn_mfma_f32_16x16x32_bf16(b3, a1, acc[1][3], 0, 0, 0);
      __builtin_amdgcn_s_setprio(0);
      __builtin_amdgcn_s_barrier();
    }
    // ---- phase 3: kh=1 reads (a2,a3); mfma m2,m3 (no stage)
    {
      const int s1 = (kg + 4) ^ rsw;
      a2 = LDA_(wr + 2 * 16 + lr, s1);
      a3 = LDA_(wr + 3 * 16 + lr, s1);
      asm volatile("s_waitcnt lgkmcnt(0)" ::: "memory");
      __builtin_amdgcn_sched_barrier(0);
      __builtin_amdgcn_s_setprio(1);
      acc[2][0] = __builtin_amdgcn_mfma_f32_16x16x32_bf16(b0, a2, acc[2][0], 0, 0, 0);
      acc[2][1] = __builtin_amdgcn_mfma_f32_16x16x32_bf16(b1, a2, acc[2][1], 0, 0, 0);
      acc[2][2] = __builtin_amdgcn_mfma_f32_16x16x32_bf16(b2, a2, acc[2][2], 0, 0, 0);
      acc[2][3] = __builtin_amdgcn_mfma_f32_16x16x32_bf16(b3, a2, acc[2][3], 0, 0, 0);
      acc[3][0] = __builtin_amdgcn_mfma_f32_16x16x32_bf16(b0, a3, acc[3][0], 0, 0, 0);
      acc[3][1] = __builtin_amdgcn_mfma_f32_16x16x32_bf16(b1, a3, acc[3][1], 0, 0, 0);
      acc[3][2] = __builtin_amdgcn_mfma_f32_16x16x32_bf16(b2, a3, acc[3][2], 0, 0, 0);
      acc[3][3] = __builtin_amdgcn_mfma_f32_16x16x32_bf16(b3, a3, acc[3][3], 0, 0, 0);
      __builtin_amdgcn_s_setprio(0);
      // no trailing barrier: next iteration's top barrier covers reuse
    }
  }
#undef STA
#undef STB
#undef LDA_
#undef LDB_

  // Epilogue: token row = bm*256 + wr + m*16 + lr; col = bn*128 + wc + kg*4.
  const int row0 = bm * 256 + wr + lr;
  const int col0 = bn * 128 + wc + kg * 4;
#pragma unroll
  for (int m = 0; m < 4; ++m) {
    const int row = row0 + m * 16;
#pragma unroll
    for (int n = 0; n < 4; ++n) {
      const int colb = col0 + n * 16;
      const float4 bv = *reinterpret_cast<const float4*>(&bias[colb]);
      union { ushort4 u; __hip_bfloat16 h[4]; } o;
      o.h[0] = __float2bfloat16(acc[m][n][0] + bv.x);
      o.h[1] = __float2bfloat16(acc[m][n][1] + bv.y);
      o.h[2] = __float2bfloat16(acc[m][n][2] + bv.z);
      o.h[3] = __float2bfloat16(acc[m][n][3] + bv.w);
      *reinterpret_cast<ushort4*>(&C[(size_t)row * 768 + colb]) = o.u;
    }
  }
}

// ---------------------------------------------------------------------------
// Kernel 3b: R11 GEMM (BK=64 dbuf, counted vmcnt, both-sides swizzle).
// EPI 3: NT resid loads + bias pinned by sched_barrier(0); plain f32x4 stores.
// EPI 4: fused g1+g2 (blockIdx.y>>1 selects {WxT,b_x,tanh->ut} vs
// {WdtT,b_dt,sigmoid->dtb}), K=256.
// ---------------------------------------------------------------------------
template <int EPI>
__global__ __launch_bounds__(256, 2) void gemm_bf16(
    const __hip_bfloat16* __restrict__ A, int lda,
    const __hip_bfloat16* __restrict__ BT,
    const float* __restrict__ bias,
    void* __restrict__ Cptr, int ldc,
    const float* __restrict__ resid,
    int K,
    const __hip_bfloat16* __restrict__ BT2,
    const float* __restrict__ bias2,
    void* __restrict__ Cptr2) {
  __shared__ __align__(16) char ldsA[2][128 * 128];
  __shared__ __align__(16) char ldsB[2][128 * 128];

  const int t = threadIdx.x;
  const int bm = blockIdx.x;
  const int bn = blockIdx.y;
  const int wave = t >> 6, lane = t & 63;
  const int wr = (wave >> 1) * 64;
  const int wc = (wave & 1) * 64;
  const int lr = lane & 15;
  const int kg = lane >> 4;
  const int rsw = lr & 7;

  const int which = (EPI == 4) ? (bn >> 1) : 0;
  const int bneff = (EPI == 4) ? (bn & 1) : bn;
  const __hip_bfloat16* Aeff = (EPI == 4 && which) ? A + SS : A;
  const __hip_bfloat16* BTeff = (EPI == 4 && which) ? BT2 : BT;
  const float* biaseff = (EPI == 4 && which) ? bias2 : bias;
  void* Ceff = (EPI == 4 && which) ? Cptr2 : Cptr;

  const int srow = lane >> 3;
  const int sg = (lane & 7) ^ srow;
  const int g_row = wave * 32 + srow;
  const __hip_bfloat16* Ab = Aeff + (size_t)(bm * 128 + g_row) * lda + sg * 8;
  const __hip_bfloat16* Bb = BTeff + (size_t)(bneff * 128 + g_row) * K + sg * 8;

  f32x4 acc[4][4] = {};

#define STAGE(d, koff)                                                        \
  {                                                                           \
    _Pragma("unroll") for (int p = 0; p < 4; ++p) {                           \
      gl_lds16(Ab + (size_t)(p * 8) * lda + (koff),                           \
               ldsA[d] + (wave * 32 + p * 8) * 128);                          \
      gl_lds16(Bb + (size_t)(p * 8) * K + (koff),                             \
               ldsB[d] + (wave * 32 + p * 8) * 128);                          \
    }                                                                         \
  }

  const int NT = K >> 6;
  STAGE(0, 0);

  for (int ti = 0; ti < NT; ++ti) {
    const int cur = ti & 1;
    if (ti + 1 < NT) {
      STAGE(cur ^ 1, (ti + 1) * 64);
      asm volatile("s_waitcnt vmcnt(8)" ::: "memory");
    } else {
      asm volatile("s_waitcnt vmcnt(0)" ::: "memory");
    }
    __builtin_amdgcn_sched_barrier(0);
    __builtin_amdgcn_s_barrier();
#pragma unroll
    for (int kh = 0; kh < 2; ++kh) {
      bf16x8 af[4], bfr[4];
#pragma unroll
      for (int m = 0; m < 4; ++m) {
        const int row = wr + m * 16 + lr;
        const int slot = (kg + kh * 4) ^ rsw;
        af[m] = *reinterpret_cast<const bf16x8*>(ldsA[cur] + row * 128 + slot * 16);
      }
#pragma unroll
      for (int n = 0; n < 4; ++n) {
        const int row = wc + n * 16 + lr;
        const int slot = (kg + kh * 4) ^ rsw;
        bfr[n] = *reinterpret_cast<const bf16x8*>(ldsB[cur] + row * 128 + slot * 16);
      }
#pragma unroll
      for (int m = 0; m < 4; ++m)
#pragma unroll
        for (int n = 0; n < 4; ++n)
          acc[m][n] = __builtin_amdgcn_mfma_f32_16x16x32_bf16(bfr[n], af[m],
                                                              acc[m][n], 0, 0, 0);
    }
    __builtin_amdgcn_sched_barrier(0);
    __builtin_amdgcn_s_barrier();
  }
#undef STAGE

  const int row0 = bm * 128 + wr + lr;
  const int col0 = bneff * 128 + wc + kg * 4;

  if (EPI == 3) {
    f32x4 rv[4][4];
    f32x4 bv[4];
#pragma unroll
    for (int n = 0; n < 4; ++n)
      bv[n] = *reinterpret_cast<const f32x4*>(&bias[col0 + n * 16]);
#pragma unroll
    for (int m = 0; m < 4; ++m) {
      const size_t rowoff = (size_t)(row0 + m * 16) * ldc;
#pragma unroll
      for (int n = 0; n < 4; ++n) {
        rv[m][n] = __builtin_nontemporal_load(
            reinterpret_cast<const f32x4*>(&resid[rowoff + col0 + n * 16]));
      }
    }
    __builtin_amdgcn_sched_barrier(0);  // pin: loads stay issued up-front
#pragma unroll
    for (int m = 0; m < 4; ++m) {
      const size_t rowoff = (size_t)(row0 + m * 16) * ldc;
#pragma unroll
      for (int n = 0; n < 4; ++n) {
        f32x4 ov = acc[m][n] + bv[n] + rv[m][n];
        *reinterpret_cast<f32x4*>(&((float*)Cptr)[rowoff + col0 + n * 16]) = ov;
      }
    }
  } else {
#pragma unroll
    for (int m = 0; m < 4; ++m) {
      const int row = row0 + m * 16;
#pragma unroll
      for (int n = 0; n < 4; ++n) {
        const int colb = col0 + n * 16;
        const float4 bvv = *reinterpret_cast<const float4*>(&biaseff[colb]);
        float v0 = acc[m][n][0] + bvv.x;
        float v1 = acc[m][n][1] + bvv.y;
        float v2 = acc[m][n][2] + bvv.z;
        float v3 = acc[m][n][3] + bvv.w;
        if (EPI == 1 || (EPI == 4 && which == 0)) {
          v0 = tanhf(v0); v1 = tanhf(v1); v2 = tanhf(v2); v3 = tanhf(v3);
        } else if (EPI == 2 || (EPI == 4 && which == 1)) {
          v0 = 1.f / (1.f + expf(-v0)); v1 = 1.f / (1.f + expf(-v1));
          v2 = 1.f / (1.f + expf(-v2)); v3 = 1.f / (1.f + expf(-v3));
        }
        union { ushort4 u; __hip_bfloat16 h[4]; } o;
        o.h[0] = __float2bfloat16(v0); o.h[1] = __float2bfloat16(v1);
        o.h[2] = __float2bfloat16(v2); o.h[3] = __float2bfloat16(v3);
        *reinterpret_cast<ushort4*>(
            &((__hip_bfloat16*)Ceff)[(size_t)row * ldc + colb]) = o.u;
      }
    }
  }
}

// ---------------------------------------------------------------------------
// Kernel 4a: chunked scan phase A.  Per (b, chunk, s): local scan from h=0
// giving h0, and decay product A = prod(1-d).  2 channels per lane (ushort2).
// ---------------------------------------------------------------------------
__global__ __launch_bounds__(128) void scan_phase_a(
    const __hip_bfloat16* __restrict__ ut,
    const __hip_bfloat16* __restrict__ dtb,
    float* __restrict__ h0s, float* __restrict__ As) {
  const int bc = blockIdx.x;             // b*CCH + c
  const int b = bc / CCH, c = bc % CCH;
  const int ch = threadIdx.x * 2;        // channel pair base
  const size_t base = ((size_t)b * LL + (size_t)c * TCH) * SS + ch;
  float h0 = 0.f, h1 = 0.f, A0 = 1.f, A1 = 1.f;
#pragma unroll 8
  for (int t = 0; t < TCH; ++t) {
    const ushort2 uu = *reinterpret_cast<const ushort2*>(ut + base + (size_t)t * SS);
    const ushort2 dd = *reinterpret_cast<const ushort2*>(dtb + base + (size_t)t * SS);
    const float d0 = bfu(dd.x), d1 = bfu(dd.y);
    h0 = fmaf(d0, bfu(uu.x) - h0, h0);
    h1 = fmaf(d1, bfu(uu.y) - h1, h1);
    A0 *= (1.f - d0);
    A1 *= (1.f - d1);
  }
  const size_t o = (size_t)bc * SS + ch;
  *reinterpret_cast<float2*>(h0s + o) = make_float2(h0, h1);
  *reinterpret_cast<float2*>(As + o) = make_float2(A0, A1);
}

// ---------------------------------------------------------------------------
// Kernel 4b: carry scan over chunk summaries.  Per (b, s): hin_0 = 0,
// hin_{c+1} = h0_c + A_c * hin_c.  Stores hin per (b, c, s).
// ---------------------------------------------------------------------------
__global__ __launch_bounds__(256) void scan_phase_b(
    const float* __restrict__ h0s, const float* __restrict__ As,
    float* __restrict__ hins) {
  const int b = blockIdx.x;
  const int s = threadIdx.x;
  float hin = 0.f;
#pragma unroll 8
  for (int c = 0; c < CCH; ++c) {
    const size_t idx = ((size_t)b * CCH + c) * SS + s;
    hins[idx] = hin;
    hin = fmaf(As[idx], hin, h0s[idx]);
  }
}

// ---------------------------------------------------------------------------
// Kernel 4c: chunked scan phase C.  Re-run each chunk with correct carry-in,
// gate by sigmoid(g), write hsg (in-place over ut: same-thread read-first).
// ---------------------------------------------------------------------------
__global__ __launch_bounds__(128) void scan_phase_c(
    const __hip_bfloat16* __restrict__ ut,
    const __hip_bfloat16* __restrict__ dtb,
    const __hip_bfloat16* __restrict__ gz,   // uzg + 512, row stride 768
    const float* __restrict__ hins,
    __hip_bfloat16* __restrict__ hsg) {
  const int bc = blockIdx.x;
  const int b = bc / CCH, c = bc % CCH;
  const int ch = threadIdx.x * 2;
  const size_t rowbase = (size_t)b * LL + (size_t)c * TCH;
  const float2 hv = *reinterpret_cast<const float2*>(hins + (size_t)bc * SS + ch);
  float h0 = hv.x, h1 = hv.y;
#pragma unroll 8
  for (int t = 0; t < TCH; ++t) {
    const size_t row = rowbase + t;
    const ushort2 uu = *reinterpret_cast<const ushort2*>(ut + row * SS + ch);
    const ushort2 dd = *reinterpret_cast<const ushort2*>(dtb + row * SS + ch);
    const ushort2 gg = *reinterpret_cast<const ushort2*>(gz + row * 768 + ch);
    h0 = fmaf(bfu(dd.x), bfu(uu.x) - h0, h0);
    h1 = fmaf(bfu(dd.y), bfu(uu.y) - h1, h1);
    union { ushort2 u; __hip_bfloat16 h[2]; } o;
    o.h[0] = __float2bfloat16(h0 / (1.f + expf(-bfu(gg.x))));
    o.h[1] = __float2bfloat16(h1 / (1.f + expf(-bfu(gg.y))));
    *reinterpret_cast<ushort2*>(hsg + row * SS + ch) = o.u;
  }
}

// ---------------------------------------------------------------------------
extern "C" void kernel_launch(void* const* d_in, const int* in_sizes, int n_in,
                              void* d_out, int out_size, void* d_ws, size_t ws_size,
                              hipStream_t stream) {
  const float* x      = (const float*)d_in[0];
  const float* w_norm = (const float*)d_in[1];
  const float* W_in   = (const float*)d_in[2];
  const float* b_in   = (const float*)d_in[3];
  const float* W_x    = (const float*)d_in[4];
  const float* b_x    = (const float*)d_in[5];
  const float* W_dt   = (const float*)d_in[6];
  const float* b_dt   = (const float*)d_in[7];
  const float* W_out  = (const float*)d_in[8];
  const float* b_out  = (const float*)d_in[9];
  float* out = (float*)d_out;

  // Workspace layout (bf16 buffers). ut/dt alias the dead xn region.
  char* w = (char*)d_ws;
  __hip_bfloat16* xn  = (__hip_bfloat16*)w;                 // NTOK*1024
  __hip_bfloat16* ut  = (__hip_bfloat16*)w;                 // NTOK*256 (after GEMM1)
  __hip_bfloat16* dtb = (__hip_bfloat16*)(w + (size_t)NTOK * SS * 2);
  w += (size_t)NTOK * DD * 2;                               // 64 MiB
  __hip_bfloat16* uzg = (__hip_bfloat16*)w;  w += (size_t)NTOK * 768 * 2;  // 48 MiB
  __hip_bfloat16* WinT  = (__hip_bfloat16*)w;  w += (size_t)768 * DD * 2;
  __hip_bfloat16* WxT   = (__hip_bfloat16*)w;  w += (size_t)SS * SS * 2;
  __hip_bfloat16* WdtT  = (__hip_bfloat16*)w;  w += (size_t)SS * SS * 2;
  __hip_bfloat16* WoutT = (__hip_bfloat16*)w;  w += (size_t)DD * SS * 2;
  float* h0s  = (float*)w;  w += (size_t)BB * CCH * SS * 4;   // 512 KiB
  float* As   = (float*)w;  w += (size_t)BB * CCH * SS * 4;
  float* hins = (float*)w;  w += (size_t)BB * CCH * SS * 4;
  (void)ws_size; (void)n_in; (void)in_sizes; (void)out_size;

  // Stage 0: all weight conversions in one launch
  convT4<<<dim3((DD * 768 + 255) / 256, 4), 256, 0, stream>>>(
      W_in, W_x, W_dt, W_out, WinT, WxT, WdtT, WoutT);

  // Stage 1: RMSNorm -> xn (bf16)
  prep_rms<<<NTOK, 256, 0, stream>>>(x, w_norm, xn);

  // Stage 2: uzg = xn @ W_in + b_in   (M=32768, N=768, K=1024), 8-phase
  gemm0_8p<<<dim3(NTOK / 256, 768 / 128), 512, 0, stream>>>(
      xn, WinT, b_in, uzg);

  // Stage 3 (fused): ut = tanh(u @ W_x + b_x); dt = sigmoid(z @ W_dt + b_dt)
  gemm_bf16<4><<<dim3(NTOK / 128, 4), 256, 0, stream>>>(
      uzg, 768, WxT, b_x, ut, SS, nullptr, SS, WdtT, b_dt, dtb);

  // Stage 4: chunked parallel scan + gate (in-place hsg over ut buffer)
  scan_phase_a<<<BB * CCH, 128, 0, stream>>>(ut, dtb, h0s, As);
  scan_phase_b<<<BB, 256, 0, stream>>>(h0s, As, hins);
  scan_phase_c<<<BB * CCH, 128, 0, stream>>>(ut, dtb, uzg + 2 * SS, hins, ut);

  // Stage 5: out = x + hsg @ W_out + b_out  (M=32768, N=1024, K=256)
  gemm_bf16<3><<<dim3(NTOK / 128, DD / 128), 256, 0, stream>>>(
      ut, SS, WoutT, b_out, out, DD, x, SS, nullptr, nullptr, nullptr);
}

// Round 14
// 269.430 us; speedup vs baseline: 1.0674x; 1.0609x over previous
//
#include <hip/hip_runtime.h>
#include <hip/hip_bf16.h>

// Problem constants (B=8, L=4096, D=1024, S=256)
#define BB 8
#define LL 4096
#define DD 1024
#define SS 256
#define NTOK (BB * LL)  // 32768 tokens
#define CCH 64          // chunks per sequence (parallel scan)
#define TCH (LL / CCH)  // 64 timesteps per chunk

typedef short bf16x8 __attribute__((ext_vector_type(8)));
typedef float f32x4 __attribute__((ext_vector_type(4)));

__device__ __forceinline__ float bfu(unsigned short v) {
  union { unsigned int i; float f; } x;
  x.i = ((unsigned int)v) << 16;
  return x.f;
}

// Async global->LDS, 16B per lane. LDS dest is wave-uniform base + lane*16.
__device__ __forceinline__ void gl_lds16(const __hip_bfloat16* g, void* l) {
  __builtin_amdgcn_global_load_lds(
      (const __attribute__((address_space(1))) unsigned int*)g,
      (__attribute__((address_space(3))) unsigned int*)l, 16, 0, 0);
}

// ---------------------------------------------------------------------------
// Kernel 1: RMSNorm + bf16 cast.  One block per token row (D=1024).
// ---------------------------------------------------------------------------
__global__ __launch_bounds__(256) void prep_rms(const float* __restrict__ x,
                                                const float* __restrict__ wn,
                                                __hip_bfloat16* __restrict__ xn) {
  const size_t row = blockIdx.x;
  const int t = threadIdx.x;
  const float4 xv = reinterpret_cast<const float4*>(x + row * DD)[t];
  const float4 wv = reinterpret_cast<const float4*>(wn)[t];
  float ss = xv.x * xv.x + xv.y * xv.y + xv.z * xv.z + xv.w * xv.w;
#pragma unroll
  for (int m = 32; m >= 1; m >>= 1) ss += __shfl_xor(ss, m);
  __shared__ float red[4];
  if ((t & 63) == 0) red[t >> 6] = ss;
  __syncthreads();
  const float tot = red[0] + red[1] + red[2] + red[3];
  const float r = rsqrtf(tot * (1.0f / DD) + 1e-8f);
  union { ushort4 u; __hip_bfloat16 h[4]; } o;
  o.h[0] = __float2bfloat16(xv.x * wv.x * r);
  o.h[1] = __float2bfloat16(xv.y * wv.y * r);
  o.h[2] = __float2bfloat16(xv.z * wv.z * r);
  o.h[3] = __float2bfloat16(xv.w * wv.w * r);
  reinterpret_cast<ushort4*>(xn + row * DD)[t] = o.u;
}

// ---------------------------------------------------------------------------
// Kernel 2: all four weight transposes+casts in one launch (blockIdx.y = seg).
// WT[n*K+k] = bf16(W[k*Nw+n])
// ---------------------------------------------------------------------------
__global__ __launch_bounds__(256) void convT4(
    const float* __restrict__ W0, const float* __restrict__ W1,
    const float* __restrict__ W2, const float* __restrict__ W3,
    __hip_bfloat16* __restrict__ T0, __hip_bfloat16* __restrict__ T1,
    __hip_bfloat16* __restrict__ T2, __hip_bfloat16* __restrict__ T3) {
  const int seg = blockIdx.y;
  const int K = (seg == 0) ? DD : SS;
  const int Nw = (seg == 0) ? 768 : (seg == 3) ? DD : SS;
  const float* W = (seg == 0) ? W0 : (seg == 1) ? W1 : (seg == 2) ? W2 : W3;
  __hip_bfloat16* T = (seg == 0) ? T0 : (seg == 1) ? T1 : (seg == 2) ? T2 : T3;
  const int idx = blockIdx.x * 256 + threadIdx.x;
  if (idx >= K * Nw) return;
  const int k = idx / Nw, n = idx % Nw;
  T[(size_t)n * K + k] = __float2bfloat16(W[idx]);
}

// ---------------------------------------------------------------------------
// Kernel 3: bf16 MFMA GEMM.  C[M,Nt] = epi(A[M,K] @ BT[Nt,K]^T + bias)
// 128x128 tile, 4 waves, BK=64, dbuf LDS, counted vmcnt (T4), both-sides
// XOR swizzle (T2/rule #21), swapped MFMA operands (row=token epilogue).
// EPI 0: XCD-aware block swizzle (T1): 1-D grid 1536 = 8 XCDs x 192;
//   consecutive blocks on one XCD enumerate bn fastest within bm, so each
//   256KB A-panel is read once per XCD L2 instead of from 6 XCDs.
// EPI 3: NT resid loads + bias pinned by sched_barrier(0); plain f32x4 stores.
// EPI 4: fused g1+g2 (blockIdx.y>>1 selects {WxT,b_x,tanh->ut} vs
// {WdtT,b_dt,sigmoid->dtb}), K=256.
// EPI: 0 = bf16, 1 = tanh, 2 = sigmoid, 3 = +resid->f32, 4 = fused g1/g2
// ---------------------------------------------------------------------------
template <int EPI>
__global__ __launch_bounds__(256, 2) void gemm_bf16(
    const __hip_bfloat16* __restrict__ A, int lda,
    const __hip_bfloat16* __restrict__ BT,
    const float* __restrict__ bias,
    void* __restrict__ Cptr, int ldc,
    const float* __restrict__ resid,
    int K,
    const __hip_bfloat16* __restrict__ BT2,
    const float* __restrict__ bias2,
    void* __restrict__ Cptr2) {
  __shared__ __align__(16) char ldsA[2][128 * 128];
  __shared__ __align__(16) char ldsB[2][128 * 128];

  const int t = threadIdx.x;
  int bm, bn;
  if (EPI == 0) {
    // T1 XCD swizzle: wg -> (xcd = wg&7) gets contiguous swz-range.
    const int wg = blockIdx.x;            // 0..1535
    const int swz = (wg & 7) * 192 + (wg >> 3);
    bm = swz / 6;                         // 0..255 (A-panel group)
    bn = swz % 6;                         // 0..5   (fastest within XCD)
  } else {
    bm = blockIdx.x;
    bn = blockIdx.y;
  }
  const int wave = t >> 6, lane = t & 63;
  const int wr = (wave >> 1) * 64;
  const int wc = (wave & 1) * 64;
  const int lr = lane & 15;
  const int kg = lane >> 4;
  const int rsw = lr & 7;

  const int which = (EPI == 4) ? (bn >> 1) : 0;
  const int bneff = (EPI == 4) ? (bn & 1) : bn;
  const __hip_bfloat16* Aeff = (EPI == 4 && which) ? A + SS : A;
  const __hip_bfloat16* BTeff = (EPI == 4 && which) ? BT2 : BT;
  const float* biaseff = (EPI == 4 && which) ? bias2 : bias;
  void* Ceff = (EPI == 4 && which) ? Cptr2 : Cptr;

  const int srow = lane >> 3;
  const int sg = (lane & 7) ^ srow;
  const int g_row = wave * 32 + srow;
  const __hip_bfloat16* Ab = Aeff + (size_t)(bm * 128 + g_row) * lda + sg * 8;
  const __hip_bfloat16* Bb = BTeff + (size_t)(bneff * 128 + g_row) * K + sg * 8;

  f32x4 acc[4][4] = {};

#define STAGE(d, koff)                                                        \
  {                                                                           \
    _Pragma("unroll") for (int p = 0; p < 4; ++p) {                           \
      gl_lds16(Ab + (size_t)(p * 8) * lda + (koff),                           \
               ldsA[d] + (wave * 32 + p * 8) * 128);                          \
      gl_lds16(Bb + (size_t)(p * 8) * K + (koff),                             \
               ldsB[d] + (wave * 32 + p * 8) * 128);                          \
    }                                                                         \
  }

  const int NT = K >> 6;
  STAGE(0, 0);

  for (int ti = 0; ti < NT; ++ti) {
    const int cur = ti & 1;
    if (ti + 1 < NT) {
      STAGE(cur ^ 1, (ti + 1) * 64);
      asm volatile("s_waitcnt vmcnt(8)" ::: "memory");
    } else {
      asm volatile("s_waitcnt vmcnt(0)" ::: "memory");
    }
    __builtin_amdgcn_sched_barrier(0);
    __builtin_amdgcn_s_barrier();
#pragma unroll
    for (int kh = 0; kh < 2; ++kh) {
      bf16x8 af[4], bfr[4];
#pragma unroll
      for (int m = 0; m < 4; ++m) {
        const int row = wr + m * 16 + lr;
        const int slot = (kg + kh * 4) ^ rsw;
        af[m] = *reinterpret_cast<const bf16x8*>(ldsA[cur] + row * 128 + slot * 16);
      }
#pragma unroll
      for (int n = 0; n < 4; ++n) {
        const int row = wc + n * 16 + lr;
        const int slot = (kg + kh * 4) ^ rsw;
        bfr[n] = *reinterpret_cast<const bf16x8*>(ldsB[cur] + row * 128 + slot * 16);
      }
#pragma unroll
      for (int m = 0; m < 4; ++m)
#pragma unroll
        for (int n = 0; n < 4; ++n)
          acc[m][n] = __builtin_amdgcn_mfma_f32_16x16x32_bf16(bfr[n], af[m],
                                                              acc[m][n], 0, 0, 0);
    }
    __builtin_amdgcn_sched_barrier(0);
    __builtin_amdgcn_s_barrier();
  }
#undef STAGE

  const int row0 = bm * 128 + wr + lr;
  const int col0 = bneff * 128 + wc + kg * 4;

  if (EPI == 3) {
    f32x4 rv[4][4];
    f32x4 bv[4];
#pragma unroll
    for (int n = 0; n < 4; ++n)
      bv[n] = *reinterpret_cast<const f32x4*>(&bias[col0 + n * 16]);
#pragma unroll
    for (int m = 0; m < 4; ++m) {
      const size_t rowoff = (size_t)(row0 + m * 16) * ldc;
#pragma unroll
      for (int n = 0; n < 4; ++n) {
        rv[m][n] = __builtin_nontemporal_load(
            reinterpret_cast<const f32x4*>(&resid[rowoff + col0 + n * 16]));
      }
    }
    __builtin_amdgcn_sched_barrier(0);  // pin: loads stay issued up-front
#pragma unroll
    for (int m = 0; m < 4; ++m) {
      const size_t rowoff = (size_t)(row0 + m * 16) * ldc;
#pragma unroll
      for (int n = 0; n < 4; ++n) {
        f32x4 ov = acc[m][n] + bv[n] + rv[m][n];
        *reinterpret_cast<f32x4*>(&((float*)Cptr)[rowoff + col0 + n * 16]) = ov;
      }
    }
  } else {
#pragma unroll
    for (int m = 0; m < 4; ++m) {
      const int row = row0 + m * 16;
#pragma unroll
      for (int n = 0; n < 4; ++n) {
        const int colb = col0 + n * 16;
        const float4 bvv = *reinterpret_cast<const float4*>(&biaseff[colb]);
        float v0 = acc[m][n][0] + bvv.x;
        float v1 = acc[m][n][1] + bvv.y;
        float v2 = acc[m][n][2] + bvv.z;
        float v3 = acc[m][n][3] + bvv.w;
        if (EPI == 1 || (EPI == 4 && which == 0)) {
          v0 = tanhf(v0); v1 = tanhf(v1); v2 = tanhf(v2); v3 = tanhf(v3);
        } else if (EPI == 2 || (EPI == 4 && which == 1)) {
          v0 = 1.f / (1.f + expf(-v0)); v1 = 1.f / (1.f + expf(-v1));
          v2 = 1.f / (1.f + expf(-v2)); v3 = 1.f / (1.f + expf(-v3));
        }
        union { ushort4 u; __hip_bfloat16 h[4]; } o;
        o.h[0] = __float2bfloat16(v0); o.h[1] = __float2bfloat16(v1);
        o.h[2] = __float2bfloat16(v2); o.h[3] = __float2bfloat16(v3);
        *reinterpret_cast<ushort4*>(
            &((__hip_bfloat16*)Ceff)[(size_t)row * ldc + colb]) = o.u;
      }
    }
  }
}

// ---------------------------------------------------------------------------
// Kernel 4a: chunked scan phase A.  Per (b, chunk, s): local scan from h=0
// giving h0, and decay product A = prod(1-d).  2 channels per lane (ushort2).
// ---------------------------------------------------------------------------
__global__ __launch_bounds__(128) void scan_phase_a(
    const __hip_bfloat16* __restrict__ ut,
    const __hip_bfloat16* __restrict__ dtb,
    float* __restrict__ h0s, float* __restrict__ As) {
  const int bc = blockIdx.x;             // b*CCH + c
  const int b = bc / CCH, c = bc % CCH;
  const int ch = threadIdx.x * 2;        // channel pair base
  const size_t base = ((size_t)b * LL + (size_t)c * TCH) * SS + ch;
  float h0 = 0.f, h1 = 0.f, A0 = 1.f, A1 = 1.f;
#pragma unroll 8
  for (int t = 0; t < TCH; ++t) {
    const ushort2 uu = *reinterpret_cast<const ushort2*>(ut + base + (size_t)t * SS);
    const ushort2 dd = *reinterpret_cast<const ushort2*>(dtb + base + (size_t)t * SS);
    const float d0 = bfu(dd.x), d1 = bfu(dd.y);
    h0 = fmaf(d0, bfu(uu.x) - h0, h0);
    h1 = fmaf(d1, bfu(uu.y) - h1, h1);
    A0 *= (1.f - d0);
    A1 *= (1.f - d1);
  }
  const size_t o = (size_t)bc * SS + ch;
  *reinterpret_cast<float2*>(h0s + o) = make_float2(h0, h1);
  *reinterpret_cast<float2*>(As + o) = make_float2(A0, A1);
}

// ---------------------------------------------------------------------------
// Kernel 4b: carry scan over chunk summaries.  Per (b, s): hin_0 = 0,
// hin_{c+1} = h0_c + A_c * hin_c.  Stores hin per (b, c, s).
// ---------------------------------------------------------------------------
__global__ __launch_bounds__(256) void scan_phase_b(
    const float* __restrict__ h0s, const float* __restrict__ As,
    float* __restrict__ hins) {
  const int b = blockIdx.x;
  const int s = threadIdx.x;
  float hin = 0.f;
#pragma unroll 8
  for (int c = 0; c < CCH; ++c) {
    const size_t idx = ((size_t)b * CCH + c) * SS + s;
    hins[idx] = hin;
    hin = fmaf(As[idx], hin, h0s[idx]);
  }
}

// ---------------------------------------------------------------------------
// Kernel 4c: chunked scan phase C.  Re-run each chunk with correct carry-in,
// gate by sigmoid(g), write hsg (in-place over ut: same-thread read-first).
// ---------------------------------------------------------------------------
__global__ __launch_bounds__(128) void scan_phase_c(
    const __hip_bfloat16* __restrict__ ut,
    const __hip_bfloat16* __restrict__ dtb,
    const __hip_bfloat16* __restrict__ gz,   // uzg + 512, row stride 768
    const float* __restrict__ hins,
    __hip_bfloat16* __restrict__ hsg) {
  const int bc = blockIdx.x;
  const int b = bc / CCH, c = bc % CCH;
  const int ch = threadIdx.x * 2;
  const size_t rowbase = (size_t)b * LL + (size_t)c * TCH;
  const float2 hv = *reinterpret_cast<const float2*>(hins + (size_t)bc * SS + ch);
  float h0 = hv.x, h1 = hv.y;
#pragma unroll 8
  for (int t = 0; t < TCH; ++t) {
    const size_t row = rowbase + t;
    const ushort2 uu = *reinterpret_cast<const ushort2*>(ut + row * SS + ch);
    const ushort2 dd = *reinterpret_cast<const ushort2*>(dtb + row * SS + ch);
    const ushort2 gg = *reinterpret_cast<const ushort2*>(gz + row * 768 + ch);
    h0 = fmaf(bfu(dd.x), bfu(uu.x) - h0, h0);
    h1 = fmaf(bfu(dd.y), bfu(uu.y) - h1, h1);
    union { ushort2 u; __hip_bfloat16 h[2]; } o;
    o.h[0] = __float2bfloat16(h0 / (1.f + expf(-bfu(gg.x))));
    o.h[1] = __float2bfloat16(h1 / (1.f + expf(-bfu(gg.y))));
    *reinterpret_cast<ushort2*>(hsg + row * SS + ch) = o.u;
  }
}

// ---------------------------------------------------------------------------
extern "C" void kernel_launch(void* const* d_in, const int* in_sizes, int n_in,
                              void* d_out, int out_size, void* d_ws, size_t ws_size,
                              hipStream_t stream) {
  const float* x      = (const float*)d_in[0];
  const float* w_norm = (const float*)d_in[1];
  const float* W_in   = (const float*)d_in[2];
  const float* b_in   = (const float*)d_in[3];
  const float* W_x    = (const float*)d_in[4];
  const float* b_x    = (const float*)d_in[5];
  const float* W_dt   = (const float*)d_in[6];
  const float* b_dt   = (const float*)d_in[7];
  const float* W_out  = (const float*)d_in[8];
  const float* b_out  = (const float*)d_in[9];
  float* out = (float*)d_out;

  // Workspace layout (bf16 buffers). ut/dt alias the dead xn region.
  char* w = (char*)d_ws;
  __hip_bfloat16* xn  = (__hip_bfloat16*)w;                 // NTOK*1024
  __hip_bfloat16* ut  = (__hip_bfloat16*)w;                 // NTOK*256 (after GEMM1)
  __hip_bfloat16* dtb = (__hip_bfloat16*)(w + (size_t)NTOK * SS * 2);
  w += (size_t)NTOK * DD * 2;                               // 64 MiB
  __hip_bfloat16* uzg = (__hip_bfloat16*)w;  w += (size_t)NTOK * 768 * 2;  // 48 MiB
  __hip_bfloat16* WinT  = (__hip_bfloat16*)w;  w += (size_t)768 * DD * 2;
  __hip_bfloat16* WxT   = (__hip_bfloat16*)w;  w += (size_t)SS * SS * 2;
  __hip_bfloat16* WdtT  = (__hip_bfloat16*)w;  w += (size_t)SS * SS * 2;
  __hip_bfloat16* WoutT = (__hip_bfloat16*)w;  w += (size_t)DD * SS * 2;
  float* h0s  = (float*)w;  w += (size_t)BB * CCH * SS * 4;   // 512 KiB
  float* As   = (float*)w;  w += (size_t)BB * CCH * SS * 4;
  float* hins = (float*)w;  w += (size_t)BB * CCH * SS * 4;
  (void)ws_size; (void)n_in; (void)in_sizes; (void)out_size;

  // Stage 0: all weight conversions in one launch
  convT4<<<dim3((DD * 768 + 255) / 256, 4), 256, 0, stream>>>(
      W_in, W_x, W_dt, W_out, WinT, WxT, WdtT, WoutT);

  // Stage 1: RMSNorm -> xn (bf16)
  prep_rms<<<NTOK, 256, 0, stream>>>(x, w_norm, xn);

  // Stage 2: uzg = xn @ W_in + b_in   (M=32768, N=768, K=1024)
  // 1-D grid, XCD-swizzled inside the kernel (T1).
  gemm_bf16<0><<<dim3(1536), 256, 0, stream>>>(
      xn, DD, WinT, b_in, uzg, 768, nullptr, DD, nullptr, nullptr, nullptr);

  // Stage 3 (fused): ut = tanh(u @ W_x + b_x); dt = sigmoid(z @ W_dt + b_dt)
  gemm_bf16<4><<<dim3(NTOK / 128, 4), 256, 0, stream>>>(
      uzg, 768, WxT, b_x, ut, SS, nullptr, SS, WdtT, b_dt, dtb);

  // Stage 4: chunked parallel scan + gate (in-place hsg over ut buffer)
  scan_phase_a<<<BB * CCH, 128, 0, stream>>>(ut, dtb, h0s, As);
  scan_phase_b<<<BB, 256, 0, stream>>>(h0s, As, hins);
  scan_phase_c<<<BB * CCH, 128, 0, stream>>>(ut, dtb, uzg + 2 * SS, hins, ut);

  // Stage 5: out = x + hsg @ W_out + b_out  (M=32768, N=1024, K=256)
  gemm_bf16<3><<<dim3(NTOK / 128, DD / 128), 256, 0, stream>>>(
      ut, SS, WoutT, b_out, out, DD, x, SS, nullptr, nullptr, nullptr);
}

// Round 15
// 268.059 us; speedup vs baseline: 1.0729x; 1.0051x over previous
//
#include <hip/hip_runtime.h>
#include <hip/hip_bf16.h>

// Problem constants (B=8, L=4096, D=1024, S=256)
#define BB 8
#define LL 4096
#define DD 1024
#define SS 256
#define NTOK (BB * LL)  // 32768 tokens
#define CCH 64          // chunks per sequence (parallel scan)
#define TCH (LL / CCH)  // 64 timesteps per chunk

typedef short bf16x8 __attribute__((ext_vector_type(8)));
typedef float f32x4 __attribute__((ext_vector_type(4)));

__device__ __forceinline__ float bfu(unsigned short v) {
  union { unsigned int i; float f; } x;
  x.i = ((unsigned int)v) << 16;
  return x.f;
}

// Async global->LDS, 16B per lane. LDS dest is wave-uniform base + lane*16.
__device__ __forceinline__ void gl_lds16(const __hip_bfloat16* g, void* l) {
  __builtin_amdgcn_global_load_lds(
      (const __attribute__((address_space(1))) unsigned int*)g,
      (__attribute__((address_space(3))) unsigned int*)l, 16, 0, 0);
}

// ---------------------------------------------------------------------------
// Kernel 1: RMSNorm + bf16 cast.  One block per token row (D=1024).
// ---------------------------------------------------------------------------
__global__ __launch_bounds__(256) void prep_rms(const float* __restrict__ x,
                                                const float* __restrict__ wn,
                                                __hip_bfloat16* __restrict__ xn) {
  const size_t row = blockIdx.x;
  const int t = threadIdx.x;
  const float4 xv = reinterpret_cast<const float4*>(x + row * DD)[t];
  const float4 wv = reinterpret_cast<const float4*>(wn)[t];
  float ss = xv.x * xv.x + xv.y * xv.y + xv.z * xv.z + xv.w * xv.w;
#pragma unroll
  for (int m = 32; m >= 1; m >>= 1) ss += __shfl_xor(ss, m);
  __shared__ float red[4];
  if ((t & 63) == 0) red[t >> 6] = ss;
  __syncthreads();
  const float tot = red[0] + red[1] + red[2] + red[3];
  const float r = rsqrtf(tot * (1.0f / DD) + 1e-8f);
  union { ushort4 u; __hip_bfloat16 h[4]; } o;
  o.h[0] = __float2bfloat16(xv.x * wv.x * r);
  o.h[1] = __float2bfloat16(xv.y * wv.y * r);
  o.h[2] = __float2bfloat16(xv.z * wv.z * r);
  o.h[3] = __float2bfloat16(xv.w * wv.w * r);
  reinterpret_cast<ushort4*>(xn + row * DD)[t] = o.u;
}

// ---------------------------------------------------------------------------
// Kernel 2: all four weight transposes+casts in one launch (blockIdx.y = seg).
// WT[n*K+k] = bf16(W[k*Nw+n])
// ---------------------------------------------------------------------------
__global__ __launch_bounds__(256) void convT4(
    const float* __restrict__ W0, const float* __restrict__ W1,
    const float* __restrict__ W2, const float* __restrict__ W3,
    __hip_bfloat16* __restrict__ T0, __hip_bfloat16* __restrict__ T1,
    __hip_bfloat16* __restrict__ T2, __hip_bfloat16* __restrict__ T3) {
  const int seg = blockIdx.y;
  const int K = (seg == 0) ? DD : SS;
  const int Nw = (seg == 0) ? 768 : (seg == 3) ? DD : SS;
  const float* W = (seg == 0) ? W0 : (seg == 1) ? W1 : (seg == 2) ? W2 : W3;
  __hip_bfloat16* T = (seg == 0) ? T0 : (seg == 1) ? T1 : (seg == 2) ? T2 : T3;
  const int idx = blockIdx.x * 256 + threadIdx.x;
  if (idx >= K * Nw) return;
  const int k = idx / Nw, n = idx % Nw;
  T[(size_t)n * K + k] = __float2bfloat16(W[idx]);
}

// ---------------------------------------------------------------------------
// Kernel 3: bf16 MFMA GEMM.  C[M,Nt] = epi(A[M,K] @ BT[Nt,K]^T + bias)
// 128x128 tile, 4 waves, BK=64, dbuf LDS, counted vmcnt (T4), both-sides
// XOR swizzle (T2/rule #21), swapped MFMA operands (row=token epilogue).
// EPI 0: XCD-aware block swizzle (T1), 1-D grid 1536 = 8 XCDs x 192.
// EPI 3: resid loads STREAMED INSIDE the K-loop (4 NT loads/iter interleaved
//   with staging; vmcnt(12) ladder keeps tile-accounting exact) -> reads
//   overlap staging across the whole kernel; epilogue = pure store burst.
// EPI 4: fused g1+g2 (blockIdx.y>>1 selects {WxT,b_x,tanh->ut} vs
// {WdtT,b_dt,sigmoid->dtb}), K=256.
// EPI: 0 = bf16, 1 = tanh, 2 = sigmoid, 3 = +resid->f32, 4 = fused g1/g2
// ---------------------------------------------------------------------------
template <int EPI>
__global__ __launch_bounds__(256, 2) void gemm_bf16(
    const __hip_bfloat16* __restrict__ A, int lda,
    const __hip_bfloat16* __restrict__ BT,
    const float* __restrict__ bias,
    void* __restrict__ Cptr, int ldc,
    const float* __restrict__ resid,
    int K,
    const __hip_bfloat16* __restrict__ BT2,
    const float* __restrict__ bias2,
    void* __restrict__ Cptr2) {
  __shared__ __align__(16) char ldsA[2][128 * 128];
  __shared__ __align__(16) char ldsB[2][128 * 128];

  const int t = threadIdx.x;
  int bm, bn;
  if (EPI == 0) {
    // T1 XCD swizzle: wg -> (xcd = wg&7) gets contiguous swz-range.
    const int wg = blockIdx.x;            // 0..1535
    const int swz = (wg & 7) * 192 + (wg >> 3);
    bm = swz / 6;                         // 0..255 (A-panel group)
    bn = swz % 6;                         // 0..5   (fastest within XCD)
  } else {
    bm = blockIdx.x;
    bn = blockIdx.y;
  }
  const int wave = t >> 6, lane = t & 63;
  const int wr = (wave >> 1) * 64;
  const int wc = (wave & 1) * 64;
  const int lr = lane & 15;
  const int kg = lane >> 4;
  const int rsw = lr & 7;

  const int which = (EPI == 4) ? (bn >> 1) : 0;
  const int bneff = (EPI == 4) ? (bn & 1) : bn;
  const __hip_bfloat16* Aeff = (EPI == 4 && which) ? A + SS : A;
  const __hip_bfloat16* BTeff = (EPI == 4 && which) ? BT2 : BT;
  const float* biaseff = (EPI == 4 && which) ? bias2 : bias;
  void* Ceff = (EPI == 4 && which) ? Cptr2 : Cptr;

  const int srow = lane >> 3;
  const int sg = (lane & 7) ^ srow;
  const int g_row = wave * 32 + srow;
  const __hip_bfloat16* Ab = Aeff + (size_t)(bm * 128 + g_row) * lda + sg * 8;
  const __hip_bfloat16* Bb = BTeff + (size_t)(bneff * 128 + g_row) * K + sg * 8;

  f32x4 acc[4][4] = {};

#define STAGE(d, koff)                                                        \
  {                                                                           \
    _Pragma("unroll") for (int p = 0; p < 4; ++p) {                           \
      gl_lds16(Ab + (size_t)(p * 8) * lda + (koff),                           \
               ldsA[d] + (wave * 32 + p * 8) * 128);                          \
      gl_lds16(Bb + (size_t)(p * 8) * K + (koff),                             \
               ldsB[d] + (wave * 32 + p * 8) * 128);                          \
    }                                                                         \
  }

  // Compute-phase body (reads buffer `cur`, does 32 MFMA).
#define KSTEP(cur)                                                            \
  {                                                                           \
    _Pragma("unroll") for (int kh = 0; kh < 2; ++kh) {                        \
      bf16x8 af[4], bfr[4];                                                   \
      _Pragma("unroll") for (int m = 0; m < 4; ++m) {                         \
        const int row = wr + m * 16 + lr;                                     \
        const int slot = (kg + kh * 4) ^ rsw;                                 \
        af[m] = *reinterpret_cast<const bf16x8*>(ldsA[cur] + row * 128 +      \
                                                 slot * 16);                  \
      }                                                                       \
      _Pragma("unroll") for (int n = 0; n < 4; ++n) {                         \
        const int row = wc + n * 16 + lr;                                     \
        const int slot = (kg + kh * 4) ^ rsw;                                 \
        bfr[n] = *reinterpret_cast<const bf16x8*>(ldsB[cur] + row * 128 +     \
                                                  slot * 16);                 \
      }                                                                       \
      _Pragma("unroll") for (int m = 0; m < 4; ++m)                           \
          _Pragma("unroll") for (int n = 0; n < 4; ++n)                       \
              acc[m][n] = __builtin_amdgcn_mfma_f32_16x16x32_bf16(            \
                  bfr[n], af[m], acc[m][n], 0, 0, 0);                         \
    }                                                                         \
  }

  const int row0 = bm * 128 + wr + lr;
  const int col0 = bneff * 128 + wc + kg * 4;

  if constexpr (EPI == 3) {
    // K = 256 (4 tiles).  Stream resid inside the loop: per iter issue
    // {4 NT resid loads + 8 staging loads}; vmcnt(12) retires exactly the
    // previous iteration's dozen (current tile landed, newer in flight).
    f32x4 rv[4][4];
    f32x4 bv[4];
#pragma unroll
    for (int n = 0; n < 4; ++n)
      bv[n] = *reinterpret_cast<const f32x4*>(&bias[col0 + n * 16]);  // 4 loads
    STAGE(0, 0);                                                      // 8 loads
#pragma unroll
    for (int ti = 0; ti < 4; ++ti) {
      const int cur = ti & 1;
      {  // resid row ti: 4 NT loads
        const size_t rowoff = (size_t)(row0 + ti * 16) * ldc;
#pragma unroll
        for (int n = 0; n < 4; ++n)
          rv[ti][n] = __builtin_nontemporal_load(
              reinterpret_cast<const f32x4*>(&resid[rowoff + col0 + n * 16]));
      }
      if (ti < 3) {
        STAGE(cur ^ 1, (ti + 1) * 64);
        asm volatile("s_waitcnt vmcnt(12)" ::: "memory");  // tile ti landed
      } else {
        asm volatile("s_waitcnt vmcnt(4)" ::: "memory");   // tile 3 landed
      }
      __builtin_amdgcn_sched_barrier(0);
      __builtin_amdgcn_s_barrier();
      KSTEP(cur)
      __builtin_amdgcn_sched_barrier(0);
      __builtin_amdgcn_s_barrier();
    }
    // Epilogue: pure store burst (resid already in registers).
#pragma unroll
    for (int m = 0; m < 4; ++m) {
      const size_t rowoff = (size_t)(row0 + m * 16) * ldc;
#pragma unroll
      for (int n = 0; n < 4; ++n) {
        f32x4 ov = acc[m][n] + bv[n] + rv[m][n];
        *reinterpret_cast<f32x4*>(&((float*)Cptr)[rowoff + col0 + n * 16]) = ov;
      }
    }
  } else {
    const int NT = K >> 6;
    STAGE(0, 0);
    for (int ti = 0; ti < NT; ++ti) {
      const int cur = ti & 1;
      if (ti + 1 < NT) {
        STAGE(cur ^ 1, (ti + 1) * 64);
        asm volatile("s_waitcnt vmcnt(8)" ::: "memory");
      } else {
        asm volatile("s_waitcnt vmcnt(0)" ::: "memory");
      }
      __builtin_amdgcn_sched_barrier(0);
      __builtin_amdgcn_s_barrier();
      KSTEP(cur)
      __builtin_amdgcn_sched_barrier(0);
      __builtin_amdgcn_s_barrier();
    }
#pragma unroll
    for (int m = 0; m < 4; ++m) {
      const int row = row0 + m * 16;
#pragma unroll
      for (int n = 0; n < 4; ++n) {
        const int colb = col0 + n * 16;
        const float4 bvv = *reinterpret_cast<const float4*>(&biaseff[colb]);
        float v0 = acc[m][n][0] + bvv.x;
        float v1 = acc[m][n][1] + bvv.y;
        float v2 = acc[m][n][2] + bvv.z;
        float v3 = acc[m][n][3] + bvv.w;
        if (EPI == 1 || (EPI == 4 && which == 0)) {
          v0 = tanhf(v0); v1 = tanhf(v1); v2 = tanhf(v2); v3 = tanhf(v3);
        } else if (EPI == 2 || (EPI == 4 && which == 1)) {
          v0 = 1.f / (1.f + expf(-v0)); v1 = 1.f / (1.f + expf(-v1));
          v2 = 1.f / (1.f + expf(-v2)); v3 = 1.f / (1.f + expf(-v3));
        }
        union { ushort4 u; __hip_bfloat16 h[4]; } o;
        o.h[0] = __float2bfloat16(v0); o.h[1] = __float2bfloat16(v1);
        o.h[2] = __float2bfloat16(v2); o.h[3] = __float2bfloat16(v3);
        *reinterpret_cast<ushort4*>(
            &((__hip_bfloat16*)Ceff)[(size_t)row * ldc + colb]) = o.u;
      }
    }
  }
#undef STAGE
#undef KSTEP
}

// ---------------------------------------------------------------------------
// Kernel 4a: chunked scan phase A.  Per (b, chunk, s): local scan from h=0
// giving h0, and decay product A = prod(1-d).  2 channels per lane (ushort2).
// ---------------------------------------------------------------------------
__global__ __launch_bounds__(128) void scan_phase_a(
    const __hip_bfloat16* __restrict__ ut,
    const __hip_bfloat16* __restrict__ dtb,
    float* __restrict__ h0s, float* __restrict__ As) {
  const int bc = blockIdx.x;             // b*CCH + c
  const int b = bc / CCH, c = bc % CCH;
  const int ch = threadIdx.x * 2;        // channel pair base
  const size_t base = ((size_t)b * LL + (size_t)c * TCH) * SS + ch;
  float h0 = 0.f, h1 = 0.f, A0 = 1.f, A1 = 1.f;
#pragma unroll 8
  for (int t = 0; t < TCH; ++t) {
    const ushort2 uu = *reinterpret_cast<const ushort2*>(ut + base + (size_t)t * SS);
    const ushort2 dd = *reinterpret_cast<const ushort2*>(dtb + base + (size_t)t * SS);
    const float d0 = bfu(dd.x), d1 = bfu(dd.y);
    h0 = fmaf(d0, bfu(uu.x) - h0, h0);
    h1 = fmaf(d1, bfu(uu.y) - h1, h1);
    A0 *= (1.f - d0);
    A1 *= (1.f - d1);
  }
  const size_t o = (size_t)bc * SS + ch;
  *reinterpret_cast<float2*>(h0s + o) = make_float2(h0, h1);
  *reinterpret_cast<float2*>(As + o) = make_float2(A0, A1);
}

// ---------------------------------------------------------------------------
// Kernel 4b: carry scan over chunk summaries.  Per (b, s): hin_0 = 0,
// hin_{c+1} = h0_c + A_c * hin_c.  Stores hin per (b, c, s).
// ---------------------------------------------------------------------------
__global__ __launch_bounds__(256) void scan_phase_b(
    const float* __restrict__ h0s, const float* __restrict__ As,
    float* __restrict__ hins) {
  const int b = blockIdx.x;
  const int s = threadIdx.x;
  float hin = 0.f;
#pragma unroll 8
  for (int c = 0; c < CCH; ++c) {
    const size_t idx = ((size_t)b * CCH + c) * SS + s;
    hins[idx] = hin;
    hin = fmaf(As[idx], hin, h0s[idx]);
  }
}

// ---------------------------------------------------------------------------
// Kernel 4c: chunked scan phase C.  Re-run each chunk with correct carry-in,
// gate by sigmoid(g), write hsg (in-place over ut: same-thread read-first).
// ---------------------------------------------------------------------------
__global__ __launch_bounds__(128) void scan_phase_c(
    const __hip_bfloat16* __restrict__ ut,
    const __hip_bfloat16* __restrict__ dtb,
    const __hip_bfloat16* __restrict__ gz,   // uzg + 512, row stride 768
    const float* __restrict__ hins,
    __hip_bfloat16* __restrict__ hsg) {
  const int bc = blockIdx.x;
  const int b = bc / CCH, c = bc % CCH;
  const int ch = threadIdx.x * 2;
  const size_t rowbase = (size_t)b * LL + (size_t)c * TCH;
  const float2 hv = *reinterpret_cast<const float2*>(hins + (size_t)bc * SS + ch);
  float h0 = hv.x, h1 = hv.y;
#pragma unroll 8
  for (int t = 0; t < TCH; ++t) {
    const size_t row = rowbase + t;
    const ushort2 uu = *reinterpret_cast<const ushort2*>(ut + row * SS + ch);
    const ushort2 dd = *reinterpret_cast<const ushort2*>(dtb + row * SS + ch);
    const ushort2 gg = *reinterpret_cast<const ushort2*>(gz + row * 768 + ch);
    h0 = fmaf(bfu(dd.x), bfu(uu.x) - h0, h0);
    h1 = fmaf(bfu(dd.y), bfu(uu.y) - h1, h1);
    union { ushort2 u; __hip_bfloat16 h[2]; } o;
    o.h[0] = __float2bfloat16(h0 / (1.f + expf(-bfu(gg.x))));
    o.h[1] = __float2bfloat16(h1 / (1.f + expf(-bfu(gg.y))));
    *reinterpret_cast<ushort2*>(hsg + row * SS + ch) = o.u;
  }
}

// ---------------------------------------------------------------------------
extern "C" void kernel_launch(void* const* d_in, const int* in_sizes, int n_in,
                              void* d_out, int out_size, void* d_ws, size_t ws_size,
                              hipStream_t stream) {
  const float* x      = (const float*)d_in[0];
  const float* w_norm = (const float*)d_in[1];
  const float* W_in   = (const float*)d_in[2];
  const float* b_in   = (const float*)d_in[3];
  const float* W_x    = (const float*)d_in[4];
  const float* b_x    = (const float*)d_in[5];
  const float* W_dt   = (const float*)d_in[6];
  const float* b_dt   = (const float*)d_in[7];
  const float* W_out  = (const float*)d_in[8];
  const float* b_out  = (const float*)d_in[9];
  float* out = (float*)d_out;

  // Workspace layout (bf16 buffers). ut/dt alias the dead xn region.
  char* w = (char*)d_ws;
  __hip_bfloat16* xn  = (__hip_bfloat16*)w;                 // NTOK*1024
  __hip_bfloat16* ut  = (__hip_bfloat16*)w;                 // NTOK*256 (after GEMM1)
  __hip_bfloat16* dtb = (__hip_bfloat16*)(w + (size_t)NTOK * SS * 2);
  w += (size_t)NTOK * DD * 2;                               // 64 MiB
  __hip_bfloat16* uzg = (__hip_bfloat16*)w;  w += (size_t)NTOK * 768 * 2;  // 48 MiB
  __hip_bfloat16* WinT  = (__hip_bfloat16*)w;  w += (size_t)768 * DD * 2;
  __hip_bfloat16* WxT   = (__hip_bfloat16*)w;  w += (size_t)SS * SS * 2;
  __hip_bfloat16* WdtT  = (__hip_bfloat16*)w;  w += (size_t)SS * SS * 2;
  __hip_bfloat16* WoutT = (__hip_bfloat16*)w;  w += (size_t)DD * SS * 2;
  float* h0s  = (float*)w;  w += (size_t)BB * CCH * SS * 4;   // 512 KiB
  float* As   = (float*)w;  w += (size_t)BB * CCH * SS * 4;
  float* hins = (float*)w;  w += (size_t)BB * CCH * SS * 4;
  (void)ws_size; (void)n_in; (void)in_sizes; (void)out_size;

  // Stage 0: all weight conversions in one launch
  convT4<<<dim3((DD * 768 + 255) / 256, 4), 256, 0, stream>>>(
      W_in, W_x, W_dt, W_out, WinT, WxT, WdtT, WoutT);

  // Stage 1: RMSNorm -> xn (bf16)
  prep_rms<<<NTOK, 256, 0, stream>>>(x, w_norm, xn);

  // Stage 2: uzg = xn @ W_in + b_in   (M=32768, N=768, K=1024)
  // 1-D grid, XCD-swizzled inside the kernel (T1).
  gemm_bf16<0><<<dim3(1536), 256, 0, stream>>>(
      xn, DD, WinT, b_in, uzg, 768, nullptr, DD, nullptr, nullptr, nullptr);

  // Stage 3 (fused): ut = tanh(u @ W_x + b_x); dt = sigmoid(z @ W_dt + b_dt)
  gemm_bf16<4><<<dim3(NTOK / 128, 4), 256, 0, stream>>>(
      uzg, 768, WxT, b_x, ut, SS, nullptr, SS, WdtT, b_dt, dtb);

  // Stage 4: chunked parallel scan + gate (in-place hsg over ut buffer)
  scan_phase_a<<<BB * CCH, 128, 0, stream>>>(ut, dtb, h0s, As);
  scan_phase_b<<<BB, 256, 0, stream>>>(h0s, As, hins);
  scan_phase_c<<<BB * CCH, 128, 0, stream>>>(ut, dtb, uzg + 2 * SS, hins, ut);

  // Stage 5: out = x + hsg @ W_out + b_out  (M=32768, N=1024, K=256)
  gemm_bf16<3><<<dim3(NTOK / 128, DD / 128), 256, 0, stream>>>(
      ut, SS, WoutT, b_out, out, DD, x, SS, nullptr, nullptr, nullptr);
}